// Round 3
// baseline (366.380 us; speedup 1.0000x reference)
//
#include <hip/hip_runtime.h>
#include <math.h>

// Problem constants
#define BB    64        // batch
#define NEC   40000     // num entities
#define NRC   500       // num relations
#define D1C   200
#define D2C   200
#define LLC   64        // literals
#define BN_EPS 1e-5f
#define LOG2E 1.4426950408889634f

// ws layout (floats):
//   xV  [B][D1]      @ 0        (bn0 output, b-major: xV[b*200+i])
//   rT  [D2][B]      @ 12800    (gathered relation rows: rT[k*64+b])
//   aT  [L][B]       @ 25600    ((n_h - c)*s, transposed)
//   wT  [L][B]       @ 29696    (gathered nf rows, transposed)
//   sl  [L]          @ 33792    (s[l] = sqrt(log2e/var_l[l]))
//   x2T [D1][B]      @ 33856    (bn1 output: x2T[j*64+b])
//   P   [B][40000]   @ 46656    (P[b][i*200+j] = sum_k r[b,k] W[k,i,j])
//   zq  [4][B][D1]   @ 2606656  (i-quarter partials of x·P)
#define WS_XV   0
#define WS_RT   12800
#define WS_AT   25600
#define WS_WT   29696
#define WS_SL   33792
#define WS_X2T  33856
#define WS_P    46656
#define WS_ZQ   2606656

// ---------------------------------------------------------------------------
// Kernel A: gathers + bn0 + literal pre-transforms. Tiny; 3 blocks.
// ---------------------------------------------------------------------------
__global__ __launch_bounds__(256) void prep_kernel(
    const int* __restrict__ e1_idx, const int* __restrict__ r_idx,
    const float* __restrict__ E, const float* __restrict__ R,
    const float* __restrict__ lits, const float* __restrict__ c,
    const float* __restrict__ var_l, const float* __restrict__ nf,
    const float* __restrict__ bn0g, const float* __restrict__ bn0b,
    float* __restrict__ ws) {
  float* xV = ws + WS_XV;
  float* rT = ws + WS_RT;
  float* aT = ws + WS_AT;
  float* wT = ws + WS_WT;
  float* sl = ws + WS_SL;
  int tid = threadIdx.x;

  if (blockIdx.x == 0) {
    // bn0 over batch axis: thread = feature j
    if (tid < D1C) {
      int j = tid;
      float sum = 0.f, sq = 0.f;
      for (int b = 0; b < BB; b++) {
        float e = E[e1_idx[b] * D1C + j];
        sum += e; sq += e * e;
      }
      float mean = sum * (1.f / 64.f);
      float var  = sq  * (1.f / 64.f) - mean * mean;
      float inv  = __builtin_amdgcn_rsqf(var + BN_EPS);
      float g    = bn0g[j] * inv;
      float be   = bn0b[j] - mean * g;
      for (int b = 0; b < BB; b++) {
        xV[b * D1C + j] = g * E[e1_idx[b] * D1C + j] + be;   // coalesced in j
      }
    }
  } else if (blockIdx.x == 1) {
    // gather R rows (transposed)
    for (int idx = tid; idx < D2C * 64; idx += 256) {
      int k = idx >> 6, b = idx & 63;
      rT[idx] = R[r_idx[b] * D2C + k];
    }
  } else {
    // literal branch precompute: aT[l][b] = (n_h - c)*s ; wT[l][b] = nf[r]
    for (int idx = tid; idx < LLC * 64; idx += 256) {
      int l = idx >> 6, b = idx & 63;
      float s = sqrtf(LOG2E / var_l[l]);
      aT[idx] = (lits[e1_idx[b] * LLC + l] - c[l]) * s;
      wT[idx] = nf[r_idx[b] * LLC + l];
    }
    if (tid < LLC) sl[tid] = sqrtf(LOG2E / var_l[tid]);
  }
}

// ---------------------------------------------------------------------------
// GEMM1: P[b][n] = sum_k rT[k][b] * W[k][n], n = i*200+j in [0,40000).
// lane = n (coalesced streamed W), r via s_load (K$-hot 12.8 KB).
// grid 625, block 512 = 8 waves x 8-b accumulators -> 16 waves/CU.
// All 8 waves share the same W stream -> 7/8 L1 hits.
// ---------------------------------------------------------------------------
__global__ __launch_bounds__(512) void gemm1_kernel(
    const float* __restrict__ W, const float* __restrict__ ws_in,
    float* __restrict__ ws_out) {
  const float* rT = ws_in + WS_RT;
  float* P = ws_out + WS_P;
  int lane = threadIdx.x & 63;
  int boff = __builtin_amdgcn_readfirstlane(threadIdx.x >> 6) * 8;
  int n = blockIdx.x * 64 + lane;

  float acc[8];
#pragma unroll
  for (int bb = 0; bb < 8; bb++) acc[bb] = 0.f;

  const float* wp = W + n;
  const float* rp = rT + boff;
#pragma unroll 2
  for (int k = 0; k < D2C; k++) {
    float w = wp[k * NEC];                 // coalesced 256B, streamed
    const float* r = rp + k * 64;          // wave-uniform -> s_load_x8
#pragma unroll
    for (int bb = 0; bb < 8; bb++) acc[bb] += r[bb] * w;
  }

#pragma unroll
  for (int bb = 0; bb < 8; bb++) P[(size_t)(boff + bb) * NEC + n] = acc[bb];
}

// ---------------------------------------------------------------------------
// Reduce: zq[iq][b][j] = sum_{i in quarter} xV[b][i] * P[b][i*200+j]
// grid (b=64, iq=4), 256 threads, lane = j (coalesced P reads).
// ---------------------------------------------------------------------------
__global__ __launch_bounds__(256) void reduce_kernel(
    const float* __restrict__ ws_in, float* __restrict__ ws_out) {
  const float* xV = ws_in + WS_XV;
  const float* P  = ws_in + WS_P;
  float* zq = ws_out + WS_ZQ;
  int b = blockIdx.x, iq = blockIdx.y;
  int j = threadIdx.x;
  if (j >= D1C) return;

  const float* pp = P + (size_t)b * NEC + iq * 50 * D1C + j;
  const float* xp = xV + b * D1C + iq * 50;    // uniform -> s_load
  float acc = 0.f;
#pragma unroll 10
  for (int ii = 0; ii < 50; ii++) acc += xp[ii] * pp[ii * D1C];

  zq[(iq * 64 + b) * D1C + j] = acc;
}

// ---------------------------------------------------------------------------
// bn1: per j, combine 4 i-quarter partials, batch stats over b, write x2T.
// grid 200 (j), 64 threads (b).
// ---------------------------------------------------------------------------
__global__ __launch_bounds__(64) void bn1_kernel(
    const float* __restrict__ ws_in, const float* __restrict__ bn1g,
    const float* __restrict__ bn1b, float* __restrict__ ws_out) {
  const float* zq = ws_in + WS_ZQ;
  float* x2T = ws_out + WS_X2T;
  int j = blockIdx.x, b = threadIdx.x;

  float v = zq[(0 * 64 + b) * D1C + j] + zq[(1 * 64 + b) * D1C + j]
          + zq[(2 * 64 + b) * D1C + j] + zq[(3 * 64 + b) * D1C + j];
  float sum = v, sq = v * v;
#pragma unroll
  for (int o = 32; o > 0; o >>= 1) {
    sum += __shfl_xor(sum, o, 64);
    sq  += __shfl_xor(sq,  o, 64);
  }
  float mean = sum * (1.f / 64.f);
  float var  = sq  * (1.f / 64.f) - mean * mean;
  float inv  = __builtin_amdgcn_rsqf(var + BN_EPS);
  float g    = bn1g[j] * inv;
  float be   = bn1b[j] - mean * g;
  x2T[j * 64 + b] = g * v + be;
}

// ---------------------------------------------------------------------------
// Final: out[b,n] = sigmoid( sum_j x2[b,j]E[n,j] + sum_l w[b,l]*exp2(-t^2) )
// grid (625 n-tiles, 2 b-halves), 256 thr = 4 waves x 8-b accumulators
// -> 5000 waves, 4.88 blocks/CU (tail-balanced). lane = n. E staged
// transposed in 4 j-quarters into one 16.6KB LDS buffer, then the same
// buffer is re-staged with scaled literals. x2/a/w reads -> s_load_x8.
// ---------------------------------------------------------------------------
__global__ __launch_bounds__(256, 4) void final_kernel(
    const float* __restrict__ E, const float* __restrict__ lits,
    const float* __restrict__ ws, float* __restrict__ out) {
  const float* aT  = ws + WS_AT;
  const float* wT  = ws + WS_WT;
  const float* sl  = ws + WS_SL;
  const float* x2T = ws + WS_X2T;

  __shared__ float S[64 * 65];   // union: E quarter [50][65] / lits [64][65]

  int n0 = blockIdx.x * 64;
  int tid = threadIdx.x;
  int lane = tid & 63;
  int boff = blockIdx.y * 32 + __builtin_amdgcn_readfirstlane(tid >> 6) * 8;

  float acc[8];
#pragma unroll
  for (int bb = 0; bb < 8; bb++) acc[bb] = 0.f;

  // ---- score_l: 4 quarters of 50 j ----
  for (int q = 0; q < 4; q++) {
    __syncthreads();
    for (int idx = tid; idx < 64 * 25; idx += 256) {
      int row = idx / 25, c2 = idx % 25;
      const float2 v = *(const float2*)(E + (n0 + row) * D1C + q * 50 + c2 * 2);
      S[(c2 * 2 + 0) * 65 + row] = v.x;
      S[(c2 * 2 + 1) * 65 + row] = v.y;
    }
    __syncthreads();
    const float* x2p = x2T + q * 50 * 64 + boff;
    for (int j = 0; j < 50; j++) {
      float ev = S[j * 65 + lane];            // stride-1 across lanes
      const float* xw = x2p + j * 64;         // wave-uniform -> s_load_x8
#pragma unroll
      for (int bb = 0; bb < 8; bb++) acc[bb] += ev * xw[bb];
    }
  }

  // ---- restage scaled literals into the same buffer ----
  __syncthreads();
  for (int idx = tid; idx < 64 * 16; idx += 256) {
    int row = idx >> 4, c4 = idx & 15;
    const float4 v = *(const float4*)(lits + (n0 + row) * LLC + c4 * 4);
    int l = c4 * 4;
    S[(l + 0) * 65 + row] = v.x * sl[l + 0];
    S[(l + 1) * 65 + row] = v.y * sl[l + 1];
    S[(l + 2) * 65 + row] = v.z * sl[l + 2];
    S[(l + 3) * 65 + row] = v.w * sl[l + 3];
  }
  __syncthreads();

  // ---- score_n: KBLN gaussian-kernel branch ----
  for (int l = 0; l < LLC; l++) {
    float lit = S[l * 65 + lane];
    const float* aw = aT + l * 64 + boff;     // wave-uniform -> s_load_x8
    const float* ww = wT + l * 64 + boff;
#pragma unroll
    for (int bb = 0; bb < 8; bb++) {
      float t = aw[bb] - lit;
      acc[bb] += ww[bb] * __builtin_amdgcn_exp2f(-t * t);
    }
  }

  // ---- sigmoid + coalesced store ----
#pragma unroll
  for (int bb = 0; bb < 8; bb++) {
    float s = acc[bb];
    float e = __builtin_amdgcn_exp2f(-LOG2E * s);
    out[(size_t)(boff + bb) * NEC + n0 + lane] = __builtin_amdgcn_rcpf(1.f + e);
  }
}

// ---------------------------------------------------------------------------
extern "C" void kernel_launch(void* const* d_in, const int* in_sizes, int n_in,
                              void* d_out, int out_size, void* d_ws, size_t ws_size,
                              hipStream_t stream) {
  (void)in_sizes; (void)n_in; (void)out_size; (void)ws_size;
  const int*   e1    = (const int*)d_in[0];
  const int*   ri    = (const int*)d_in[1];
  const float* E     = (const float*)d_in[2];
  const float* R     = (const float*)d_in[3];
  const float* W     = (const float*)d_in[4];
  const float* lits  = (const float*)d_in[5];
  const float* c     = (const float*)d_in[6];
  const float* var_l = (const float*)d_in[7];
  const float* nf    = (const float*)d_in[8];
  const float* bn0g  = (const float*)d_in[9];
  const float* bn0b  = (const float*)d_in[10];
  const float* bn1g  = (const float*)d_in[11];
  const float* bn1b  = (const float*)d_in[12];
  float* out = (float*)d_out;
  float* ws  = (float*)d_ws;

  prep_kernel<<<3, 256, 0, stream>>>(e1, ri, E, R, lits, c, var_l, nf,
                                     bn0g, bn0b, ws);
  gemm1_kernel<<<625, 512, 0, stream>>>(W, ws, ws);
  reduce_kernel<<<dim3(64, 4), 256, 0, stream>>>(ws, ws);
  bn1_kernel<<<200, 64, 0, stream>>>(ws, bn1g, bn1b, ws);
  final_kernel<<<dim3(625, 2), 256, 0, stream>>>(E, lits, ws, out);
}

// Round 4
// 218.731 us; speedup vs baseline: 1.6750x; 1.6750x over previous
//
#include <hip/hip_runtime.h>
#include <math.h>

// Problem constants
#define BB    64        // batch
#define NEC   40000     // num entities
#define NRC   500       // num relations
#define D1C   200
#define D2C   200
#define LLC   64        // literals
#define BN_EPS 1e-5f
#define LOG2E 1.4426950408889634f

// ws layout (floats):
//   xT   [D1][64]   @ 0       (bn0 output, transposed: xT[i*64+b])
//   rT   [D2][64]   @ 12800   (gathered relation rows, rT[k*64+b])
//   taT  [L ][64]   @ 25600   (2*(n_h - c)*s, transposed)
//   wT   [L ][64]   @ 29696   (nf[r] * exp2(-a^2), transposed)
//   sl   [L ]       @ 33792   (s[l] = sqrt(log2e/var_l[l]))
//   x2T  [D1][64]   @ 33856   (bn1 output, transposed)
//   y    [k][j][64] @ 46656   (per-k partials, r folded in)  2,560,000 floats
#define WS_XT   0
#define WS_RT   12800
#define WS_AT   25600
#define WS_WT   29696
#define WS_SL   33792
#define WS_X2T  33856
#define WS_Y    46656

// ---------------------------------------------------------------------------
// Kernel A: gathers + bn0 + literal pre-transforms. Tiny; 3 blocks.
// ---------------------------------------------------------------------------
__global__ __launch_bounds__(256) void prep_kernel(
    const int* __restrict__ e1_idx, const int* __restrict__ r_idx,
    const float* __restrict__ E, const float* __restrict__ R,
    const float* __restrict__ lits, const float* __restrict__ c,
    const float* __restrict__ var_l, const float* __restrict__ nf,
    const float* __restrict__ bn0g, const float* __restrict__ bn0b,
    float* __restrict__ ws) {
  float* xT  = ws + WS_XT;
  float* rT  = ws + WS_RT;
  float* taT = ws + WS_AT;
  float* wT  = ws + WS_WT;
  float* sl  = ws + WS_SL;
  int tid = threadIdx.x;

  if (blockIdx.x == 0) {
    // bn0 over batch axis: thread = feature j
    if (tid < D1C) {
      int j = tid;
      float sum = 0.f, sq = 0.f;
      for (int b = 0; b < BB; b++) {
        float e = E[e1_idx[b] * D1C + j];
        sum += e; sq += e * e;
      }
      float mean = sum * (1.f / 64.f);
      float var  = sq  * (1.f / 64.f) - mean * mean;
      float inv  = __builtin_amdgcn_rsqf(var + BN_EPS);
      float g    = bn0g[j] * inv;
      float be   = bn0b[j] - mean * g;
      for (int b = 0; b < BB; b++) {
        xT[j * 64 + b] = g * E[e1_idx[b] * D1C + j] + be;
      }
    }
  } else if (blockIdx.x == 1) {
    // gather R rows (transposed)
    for (int idx = tid; idx < D2C * 64; idx += 256) {
      int k = idx >> 6, b = idx & 63;
      rT[idx] = R[r_idx[b] * D2C + k];
    }
  } else {
    // literal branch precompute with the exp2 split:
    //   w*exp2(-(a-L)^2) = [w*exp2(-a^2)] * exp2(fma(2a, L, -L^2))
    // store taT = 2a, wT = w*exp2(-a^2)
    for (int idx = tid; idx < LLC * 64; idx += 256) {
      int l = idx >> 6, b = idx & 63;
      float s = sqrtf(LOG2E / var_l[l]);
      float a = (lits[e1_idx[b] * LLC + l] - c[l]) * s;
      taT[idx] = a + a;
      wT[idx]  = nf[r_idx[b] * LLC + l] * __builtin_amdgcn_exp2f(-a * a);
    }
    if (tid < LLC) sl[tid] = sqrtf(LOG2E / var_l[tid]);
  }
}

// ---------------------------------------------------------------------------
// Stage 1: y[k][j][b] = r[b,k] * sum_i x[b,i] * W[k,i,j]
// lane = b (64 exactly). W row values are wave-uniform -> s_load.
// grid (k=200, jq=10), block 128 (2 waves x 10-j tiles) -> 4000 waves.
// (Round-2 config: measured middle-pipeline total ~21 us.)
// ---------------------------------------------------------------------------
__global__ __launch_bounds__(128) void stage1_kernel(
    const float* __restrict__ W, const float* __restrict__ ws_in,
    float* __restrict__ y) {
  const float* xT = ws_in + WS_XT;
  const float* rT = ws_in + WS_RT;
  int k = blockIdx.x, jq = blockIdx.y;
  int lane = threadIdx.x & 63;
  int wid = __builtin_amdgcn_readfirstlane(threadIdx.x >> 6);
  int j0 = jq * 20 + wid * 10;

  float r = rT[k * 64 + lane];
  float acc[10];
#pragma unroll
  for (int jj = 0; jj < 10; jj++) acc[jj] = 0.f;

  const float* Wk = W + (k * D1C) * D1C + j0;   // W[k][i][j0..]
  for (int i = 0; i < D1C; i++) {
    float xv = xT[i * 64 + lane];               // coalesced, L1-hot
    const float* wr = Wk + i * D1C;             // wave-uniform -> s_load
#pragma unroll
    for (int jj = 0; jj < 10; jj++) acc[jj] += xv * wr[jj];
  }

  float* yo = y + (k * D1C + j0) * 64 + lane;
#pragma unroll
  for (int jj = 0; jj < 10; jj++) yo[jj * 64] = r * acc[jj];
}

// ---------------------------------------------------------------------------
// Kernel C: x_out[b,j] = sum_k y[k][j][b], then bn1 over b -> x2T[j][b]
// block = j (200 blocks), 256 threads: lane=b, 4 k-quarters.
// ---------------------------------------------------------------------------
__global__ __launch_bounds__(256) void reduce_bn1_kernel(
    const float* __restrict__ y, const float* __restrict__ bn1g,
    const float* __restrict__ bn1b, float* __restrict__ ws) {
  float* x2T = ws + WS_X2T;
  int j = blockIdx.x;
  int tid = threadIdx.x, b = tid & 63, kq = tid >> 6;

  float s = 0.f;
  const float* yp = y + (kq * 50 * D1C + j) * 64 + b;
  for (int k = 0; k < 50; k++) s += yp[k * D1C * 64];

  __shared__ float part[256];
  part[tid] = s;
  __syncthreads();
  if (tid < 64) {
    float v = part[tid] + part[64 + tid] + part[128 + tid] + part[192 + tid];
    float sum = v, sq = v * v;
#pragma unroll
    for (int o = 32; o > 0; o >>= 1) {
      sum += __shfl_xor(sum, o, 64);
      sq  += __shfl_xor(sq,  o, 64);
    }
    float mean = sum * (1.f / 64.f);
    float var  = sq  * (1.f / 64.f) - mean * mean;
    float inv  = __builtin_amdgcn_rsqf(var + BN_EPS);
    float g    = bn1g[j] * inv;
    float be   = bn1b[j] - mean * g;
    x2T[j * 64 + tid] = g * v + be;
  }
}

// ---------------------------------------------------------------------------
// Final: out[b,n] = sigmoid( sum_j x2[b,j]E[n,j]
//                          + sum_l w'[b,l]*exp2(fma(2a[b,l], L[n,l], -L^2)) )
// grid 625 (n-tiles of 64), 256 thr = 4 waves x 16-b accumulators.
// DOUBLE-BUFFERED staging: quarter q+1 of E (and finally the scaled-lits
// tile) is staged into the idle LDS buffer while quarter q computes ->
// 5 barriers instead of 10, global latency hidden behind the j-loop.
// x2/2a/w' reads are wave-uniform -> s_load_x16.
// ---------------------------------------------------------------------------
__global__ __launch_bounds__(256, 4) void final_kernel(
    const float* __restrict__ E, const float* __restrict__ lits,
    const float* __restrict__ ws, float* __restrict__ out) {
  const float* taT = ws + WS_AT;
  const float* wT  = ws + WS_WT;
  const float* sl  = ws + WS_SL;
  const float* x2T = ws + WS_X2T;

  __shared__ float Sa[64 * 65];
  __shared__ float Sb[64 * 65];

  int n0 = blockIdx.x * 64;
  int tid = threadIdx.x;
  int lane = tid & 63;
  int boff = __builtin_amdgcn_readfirstlane(tid >> 6) * 16;

  // stage E quarter q transposed: S[j_local*65 + row]
  auto stageE = [&](float* S, int q) {
    for (int idx = tid; idx < 64 * 25; idx += 256) {
      int row = idx / 25, c2 = idx % 25;
      const float2 v = *(const float2*)(E + (n0 + row) * D1C + q * 50 + c2 * 2);
      S[(c2 * 2 + 0) * 65 + row] = v.x;
      S[(c2 * 2 + 1) * 65 + row] = v.y;
    }
  };

  float acc[16];
#pragma unroll
  for (int bb = 0; bb < 16; bb++) acc[bb] = 0.f;

  stageE(Sa, 0);
  __syncthreads();

#pragma unroll
  for (int q = 0; q < 4; q++) {
    float* cur = (q & 1) ? Sb : Sa;
    float* nxt = (q & 1) ? Sa : Sb;
    if (q < 3) {
      stageE(nxt, q + 1);
    } else {
      // stage scaled literals L = lit*s into the idle buffer (Sa)
      for (int idx = tid; idx < 64 * 16; idx += 256) {
        int row = idx >> 4, c4 = idx & 15;
        const float4 v = *(const float4*)(lits + (n0 + row) * LLC + c4 * 4);
        int l = c4 * 4;
        nxt[(l + 0) * 65 + row] = v.x * sl[l + 0];
        nxt[(l + 1) * 65 + row] = v.y * sl[l + 1];
        nxt[(l + 2) * 65 + row] = v.z * sl[l + 2];
        nxt[(l + 3) * 65 + row] = v.w * sl[l + 3];
      }
    }
    const float* x2p = x2T + q * 50 * 64 + boff;
    for (int j = 0; j < 50; j++) {
      float ev = cur[j * 65 + lane];          // stride-1 across lanes
      const float* xw = x2p + j * 64;         // wave-uniform -> s_load_x16
#pragma unroll
      for (int bb = 0; bb < 16; bb++) acc[bb] += ev * xw[bb];
    }
    __syncthreads();
  }

  // ---- score_n: 3 VALU per (l,b) term ----
  for (int l = 0; l < LLC; l++) {
    float L = Sa[l * 65 + lane];
    float nl2 = -L * L;
    const float* aw = taT + l * 64 + boff;    // wave-uniform -> s_load_x16
    const float* ww = wT + l * 64 + boff;
#pragma unroll
    for (int bb = 0; bb < 16; bb++) {
      float e = __builtin_fmaf(aw[bb], L, nl2);
      acc[bb] += ww[bb] * __builtin_amdgcn_exp2f(e);
    }
  }

  // ---- sigmoid + coalesced store ----
#pragma unroll
  for (int bb = 0; bb < 16; bb++) {
    float s = acc[bb];
    float e = __builtin_amdgcn_exp2f(-LOG2E * s);
    out[(boff + bb) * NEC + n0 + lane] = __builtin_amdgcn_rcpf(1.f + e);
  }
}

// ---------------------------------------------------------------------------
extern "C" void kernel_launch(void* const* d_in, const int* in_sizes, int n_in,
                              void* d_out, int out_size, void* d_ws, size_t ws_size,
                              hipStream_t stream) {
  (void)in_sizes; (void)n_in; (void)out_size; (void)ws_size;
  const int*   e1    = (const int*)d_in[0];
  const int*   ri    = (const int*)d_in[1];
  const float* E     = (const float*)d_in[2];
  const float* R     = (const float*)d_in[3];
  const float* W     = (const float*)d_in[4];
  const float* lits  = (const float*)d_in[5];
  const float* c     = (const float*)d_in[6];
  const float* var_l = (const float*)d_in[7];
  const float* nf    = (const float*)d_in[8];
  const float* bn0g  = (const float*)d_in[9];
  const float* bn0b  = (const float*)d_in[10];
  const float* bn1g  = (const float*)d_in[11];
  const float* bn1b  = (const float*)d_in[12];
  float* out = (float*)d_out;
  float* ws  = (float*)d_ws;
  float* y   = ws + WS_Y;

  prep_kernel<<<3, 256, 0, stream>>>(e1, ri, E, R, lits, c, var_l, nf,
                                     bn0g, bn0b, ws);
  stage1_kernel<<<dim3(200, 10), 128, 0, stream>>>(W, ws, y);
  reduce_bn1_kernel<<<200, 256, 0, stream>>>(y, bn1g, bn1b, ws);
  final_kernel<<<625, 256, 0, stream>>>(E, lits, ws, out);
}